// Round 6
// baseline (148.361 us; speedup 1.0000x reference)
//
#include <hip/hip_runtime.h>
#include <stdint.h>

typedef unsigned int u32;
typedef unsigned long long u64;

#define N_ITEMS 131072
#define NB 131072                   // buckets (monotone in descending score)
#define NSLICE 4                    // XCD-sliced histogram copies
#define MBLK 64                     // solver blocks
#define BUCK_PER_BLK 2048           // buckets per solver block
#define CH_PER_BLK 32               // chunks (64 buckets) per solver block
#define PAD 65                      // padded LDS record stride per chunk
#define REGSLOT 2048                // record slots per region in global REC
#define FPAD 16                     // u64s per flag slot -> 128B (own cacheline)
#define CAPL 2176                   // LDS merge: left-stack capacity (records)
#define CAPS 2048                   // LDS merge: incoming-stack capacity
#define FIXSCALE 268435456.0f       // 2^28 fixed-point scale for sum(exp)
#define FIXMASK ((1ull << 46) - 1)

// ---------- helpers ----------

// sum_{i=s}^{e} (N - i) — exact weight-side sum of exp(w) over sorted positions
__device__ __forceinline__ float wsumf(int s, int e) {
  return 0.5f * (float)(e - s + 1) * (float)(2 * N_ITEMS - s - e);
}

__device__ __forceinline__ float key_to_score(u32 key) {
  u32 m = ~key;
  u32 u = (m & 0x80000000u) ? (m ^ 0x80000000u) : ~m;
  return __uint_as_float(u);
}

#define LOG2E 1.4426950408889634f
__device__ __forceinline__ float fexp(float x) { return exp2f(x * LOG2E); }

// ascending key == descending score; ascending bucket == descending score
__device__ __forceinline__ u32 bucket_of(u32 key, u32 kmin, u32 kmax) {
  double scale = (double)NB / ((double)(kmax - kmin) + 1.0);
  u32 b = (u32)((double)(key - kmin) * scale);
  return b < NB ? b : (NB - 1);
}

__device__ __forceinline__ float recSY(int2 r) { return __int_as_float(r.y); }

// relaxed agent-scope load: polls WITHOUT taking exclusive line ownership
__device__ __forceinline__ u64 agent_ld(const u64* p) {
  return __hip_atomic_load(p, __ATOMIC_RELAXED, __HIP_MEMORY_SCOPE_AGENT);
}

// ---- GLOBAL-memory pairwise region merge (fallback path; measured-correct) ----
__device__ int merge_step(int2* __restrict__ REC, int slotL, int nL,
                          int slotR, int nR, int gstartR, int gendR,
                          int t, int* shInt) {
  if (t == 0) {
    int a = 0, bb = 0, hasM = 0;
    if (nL > 0 && nR > 0) {
      int2 rL = REC[slotL + nL - 1];
      float SYL = recSY(rL); int stL = rL.x;
      int2 rR = REC[slotR];
      float SYR = recSY(rR);
      int eR = (nR > 1) ? (REC[slotR + 1].x - 1) : (gendR - 1);
      float SWL = wsumf(stL, gstartR - 1);
      float SWR = wsumf(gstartR, eR);
      if (SYL * SWR <= SYR * SWL) {
        hasM = 1;
        float SYM = SYL + SYR; int Ms = stL, Me = eR;
        a = 1; bb = 1;
        for (;;) {
          float SWM = wsumf(Ms, Me);
          if (a < nL) {
            int2 re = REC[slotL + nL - 1 - a];
            float SYe = recSY(re); int ste = re.x;
            float SWe = wsumf(ste, Ms - 1);
            if (SYe * SWM <= SYM * SWe) { SYM += SYe; Ms = ste; ++a; continue; }
          }
          if (bb < nR) {
            int2 rb = REC[slotR + bb];
            float SYb = recSY(rb); int sb = rb.x;
            int eb = (bb + 1 < nR) ? (REC[slotR + bb + 1].x - 1) : (gendR - 1);
            float SWb = wsumf(sb, eb);
            if (SYM * SWb <= SYb * SWM) { SYM += SYb; Me = eb; ++bb; continue; }
          }
          break;
        }
        REC[slotL + nL - a] = make_int2(Ms, __float_as_int(SYM));
      }
    }
    shInt[0] = a; shInt[1] = bb; shInt[2] = hasM;
  }
  __syncthreads();
  int a = shInt[0], bb = shInt[1], hasM = shInt[2];
  int destBase = slotL + nL - a + hasM;
  int srcBase = slotR + bb;
  int ncopy = nR - bb;
  if (destBase != srcBase) {
    for (int off = 0; off < ncopy; off += 2048) {
      int2 v[8];
#pragma unroll
      for (int j = 0; j < 8; ++j) {
        int k2 = off + j * 256 + t;
        if (k2 < ncopy) v[j] = REC[srcBase + k2];
      }
      __syncthreads();
#pragma unroll
      for (int j = 0; j < 8; ++j) {
        int k2 = off + j * 256 + t;
        if (k2 < ncopy) REC[destBase + k2] = v[j];
      }
      __syncthreads();
    }
  }
  __syncthreads();
  return nL - a + hasM + ncopy;
}

// ---- LDS cascade walk (t0 only): left stack mST/mSY[0..n), incoming sST/sSY[0..nR) ----
__device__ void lds_cascade(int* mST, float* mSY, int n,
                            const int* sST, const float* sSY, int nR,
                            int gstartR, int gendR, int* shInt) {
  int a = 0, bb = 0, hasM = 0;
  if (n > 0 && nR > 0) {
    float SYL = mSY[n - 1]; int stL = mST[n - 1];
    float SYR = sSY[0];
    int eR = (nR > 1) ? (sST[1] - 1) : (gendR - 1);
    float SWL = wsumf(stL, gstartR - 1);
    float SWR = wsumf(gstartR, eR);
    if (SYL * SWR <= SYR * SWL) {
      hasM = 1;
      float SYM = SYL + SYR; int Ms = stL, Me = eR;
      a = 1; bb = 1;
      for (;;) {
        float SWM = wsumf(Ms, Me);
        if (a < n) {
          float SYe = mSY[n - 1 - a]; int ste = mST[n - 1 - a];
          float SWe = wsumf(ste, Ms - 1);
          if (SYe * SWM <= SYM * SWe) { SYM += SYe; Ms = ste; ++a; continue; }
        }
        if (bb < nR) {
          float SYb = sSY[bb]; int sb = sST[bb];
          int eb = (bb + 1 < nR) ? (sST[bb + 1] - 1) : (gendR - 1);
          float SWb = wsumf(sb, eb);
          if (SYM * SWb <= SYb * SWM) { SYM += SYb; Me = eb; ++bb; continue; }
        }
        break;
      }
      mST[n - a] = Ms; mSY[n - a] = SYM;
    }
  }
  shInt[0] = a; shInt[1] = bb; shInt[2] = hasM;
}

// ---------- 1) scores -> keys; per-block minmax; zero hist/flags ----------

__global__ __launch_bounds__(256) void score_key_kernel(
    const float* __restrict__ x,
    const float* __restrict__ w1, const float* __restrict__ b1,
    const float* __restrict__ w2, const float* __restrict__ b2,
    u32* __restrict__ keyRaw, u32* __restrict__ pmin, u32* __restrict__ pmax,
    u64* __restrict__ hist8, u64* __restrict__ flags, u64* __restrict__ grpf,
    u64* __restrict__ ownf) {
  __shared__ u32 wmn[4], wmx[4];
  int t = threadIdx.x;
  int i = blockIdx.x * 256 + t;
  // zero the 4 MB sliced histogram (2 x uint4 per thread, coalesced)
  uint4 z = make_uint4(0u, 0u, 0u, 0u);
  ((uint4*)hist8)[i] = z;
  ((uint4*)hist8)[i + N_ITEMS] = z;
  if (i < MBLK) flags[(size_t)i * FPAD] = 0ull;
  if (i < 8) grpf[(size_t)i * FPAD] = 0ull;
  if (i < 512) ownf[(size_t)i * FPAD] = 0ull;
  float xv = x[i];
  float s = b2[0];
#pragma unroll
  for (int j = 0; j < 32; ++j) {
    float h = fmaf(xv, w1[j], b1[j]);
    h = fmaxf(h, 0.0f);
    s = fmaf(h, w2[j], s);
  }
  u32 u = __float_as_uint(s);
  u32 m = u ^ ((u & 0x80000000u) ? 0xFFFFFFFFu : 0x80000000u); // ascending map
  u32 key = ~m;
  keyRaw[i] = key;
  u32 mn = key, mx = key;
#pragma unroll
  for (int off = 32; off > 0; off >>= 1) {
    mn = min(mn, (u32)__shfl_xor((int)mn, off));
    mx = max(mx, (u32)__shfl_xor((int)mx, off));
  }
  if ((t & 63) == 0) { wmn[t >> 6] = mn; wmx[t >> 6] = mx; }
  __syncthreads();
  if (t == 0) {
    mn = min(min(wmn[0], wmn[1]), min(wmn[2], wmn[3]));
    mx = max(max(wmx[0], wmx[1]), max(wmx[2], wmx[3]));
    pmin[blockIdx.x] = mn;
    pmax[blockIdx.x] = mx;
  }
}

// ---------- 2) bucket aggregates: ONE packed u64 atomic per item, XCD-sliced ----------
// bits [46:63] = count, bits [0:45] = fixed-point (2^28) sum of exp(s - smax)

__global__ __launch_bounds__(256) void hist_kernel(
    const u32* __restrict__ keyRaw,
    const u32* __restrict__ pmin, const u32* __restrict__ pmax,
    u64* __restrict__ hist8, u32* __restrict__ mm) {
  __shared__ u32 s0[256], s1[256];
  int t = threadIdx.x;
  s0[t] = min(pmin[t], pmin[t + 256]);
  s1[t] = max(pmax[t], pmax[t + 256]);
  __syncthreads();
  for (int off = 128; off > 0; off >>= 1) {
    if (t < off) { s0[t] = min(s0[t], s0[t + off]); s1[t] = max(s1[t], s1[t + off]); }
    __syncthreads();
  }
  u32 kmin = s0[0], kmax = s1[0];
  if (blockIdx.x == 0 && t == 0) { mm[0] = kmin; mm[1] = kmax; }
  int i = blockIdx.x * 256 + t;
  u32 key = keyRaw[i];
  u32 g = bucket_of(key, kmin, kmax);
  float smax = key_to_score(kmin);
  float v = fexp(key_to_score(key) - smax);            // in (0, 1]
  u64 fix = (u64)fmaxf(1.0f, fmaf(v, FIXSCALE, 0.5f)); // clamp: SY can never be 0
  size_t slice = (size_t)(blockIdx.x & (NSLICE - 1)) * NB;
  atomicAdd(&hist8[slice + g], (1ull << 46) | fix);
}

// ---------- 3) scan + PAV + in-LDS merges -> 64 region stacks ----------

__global__ __launch_bounds__(256) void scan_pav_kernel(
    const u64* __restrict__ hist8, u64* __restrict__ flags,
    u32* __restrict__ cdf, int2* __restrict__ REC,
    int* __restrict__ cnt2, u32* __restrict__ rstart) {
  __shared__ u32 vals[BUCK_PER_BLK + 1];   // counts -> global-exclusive cdf
  __shared__ float seL[BUCK_PER_BLK];
  __shared__ int   rST[CH_PER_BLK * PAD];
  __shared__ float rSY[CH_PER_BLK * PAD];
  __shared__ u32 wsum[4];
  __shared__ u32 regS[65];
  __shared__ int lcnt[CH_PER_BLK];
  __shared__ int ca[16], cb[16], cM[16];
  int t = threadIdx.x, b = blockIdx.x;
  int B0 = b * BUCK_PER_BLK;
  // coalesced load + slice reduce
  for (int q = 0; q < 8; ++q) {
    int ii = q * 256 + t;
    u64 acc = 0;
#pragma unroll
    for (int c = 0; c < NSLICE; ++c) acc += hist8[(size_t)c * NB + B0 + ii];
    vals[ii] = (u32)(acc >> 46);
    seL[ii] = (float)(acc & FIXMASK) * (1.0f / FIXSCALE);
  }
  __syncthreads();
  // per-thread local prefix over contiguous 8, then wave shfl scan + 4-wave combine
  u32 loc[8]; u32 s = 0;
  for (int q = 0; q < 8; ++q) { loc[q] = s; s += vals[t * 8 + q]; }
  u32 inc = s;
#pragma unroll
  for (int off = 1; off < 64; off <<= 1) {
    u32 o2 = (u32)__shfl_up((int)inc, off);
    if ((t & 63) >= off) inc += o2;
  }
  if ((t & 63) == 63) wsum[t >> 6] = inc;
  __syncthreads();
  u32 w = (u32)(t >> 6);
  u32 woff = 0;
  if (w > 0) woff += wsum[0];
  if (w > 1) woff += wsum[1];
  if (w > 2) woff += wsum[2];
  u32 total = wsum[0] + wsum[1] + wsum[2] + wsum[3];
  u32 texcl = woff + inc - s;
  // publish aggregate; wait-all over 64 blocks (64 distinct lines, 64 pollers: safe)
  if (t == 0) atomicExch(&flags[(size_t)b * FPAD], (1ull << 32) | (u64)total);
  if (t < 64) {
    u64 f;
    do { f = agent_ld(&flags[(size_t)t * FPAD]); } while ((u32)(f >> 32) == 0u);
    u32 v = (u32)f, inc2 = v;
#pragma unroll
    for (int off = 1; off < 64; off <<= 1) {
      u32 o2 = (u32)__shfl_up((int)inc2, off);
      if (t >= off) inc2 += o2;
    }
    regS[t] = inc2 - v;
    if (t == 63) regS[64] = inc2;          // == N_ITEMS
  }
  __syncthreads();
  u32 exclu = regS[b];
  u32 tbase = texcl + exclu;
  // overwrite vals with GLOBAL exclusive cdf; mirror to global (vectorized)
  u32 eb8[8];
  for (int q = 0; q < 8; ++q) { eb8[q] = tbase + loc[q]; vals[t * 8 + q] = eb8[q]; }
  {
    uint4* c4 = (uint4*)(cdf + B0 + t * 8);
    c4[0] = make_uint4(eb8[0], eb8[1], eb8[2], eb8[3]);
    c4[1] = make_uint4(eb8[4], eb8[5], eb8[6], eb8[7]);
  }
  if (t == 255) vals[BUCK_PER_BLK] = exclu + total;
  if (b == 0 && t < 65) rstart[t] = regS[t];
  __syncthreads();
  // per-chunk PAV (32 threads), stack stored in place at padded stride
  if (t < CH_PER_BLK) {
    int base = t * PAD;
    int ptr = 0; bool have = false;
    float syT = 0.0f; int stT = 0;
    for (int k = 0; k < 64; ++k) {
      u32 cs = vals[t * 64 + k], ce = vals[t * 64 + k + 1];
      if (ce == cs) continue;                 // empty bucket
      float syC = seL[t * 64 + k];
      int stC = (int)cs, eC = (int)ce - 1;
      while (have) {
        float SWc = wsumf(stC, eC);
        float SWt = wsumf(stT, stC - 1);
        if (!(syT * SWc <= syC * SWt)) break; // merge while val_top <= val_cur
        syC += syT; stC = stT;
        if (ptr == 0) { have = false; break; }
        --ptr;
        stT = rST[base + ptr]; syT = rSY[base + ptr];
      }
      if (have) { rST[base + ptr] = stT; rSY[base + ptr] = syT; ++ptr; }
      stT = stC; syT = syC; have = true;
    }
    if (have) { rST[base + ptr] = stT; rSY[base + ptr] = syT; ++ptr; }
    lcnt[t] = ptr;
  }
  __syncthreads();
  // merge levels 0..4 entirely in LDS; copies wave-parallel across disjoint pairs
  for (int j = 0; j < 5; ++j) {
    int P = CH_PER_BLK >> (j + 1);
    if (t < P) {
      int p = t;
      int kL = p << (j + 1), kR = kL + (1 << j);
      int slotL = kL * PAD, slotR = kR * PAD;
      int nL = lcnt[kL], nR = lcnt[kR];
      int a = 0, bb = 0, hasM = 0;
      if (nL > 0 && nR > 0) {
        int gstartR = (int)vals[kR * 64];
        int gendR   = (int)vals[(kR + (1 << j)) * 64];
        float SYL = rSY[slotL + nL - 1]; int stL = rST[slotL + nL - 1];
        float SYR = rSY[slotR];
        int eR = (nR > 1) ? (rST[slotR + 1] - 1) : (gendR - 1);
        float SWL = wsumf(stL, gstartR - 1);
        float SWR = wsumf(gstartR, eR);
        if (SYL * SWR <= SYR * SWL) {
          hasM = 1;
          float SYM = SYL + SYR; int Ms = stL, Me = eR;
          a = 1; bb = 1;
          for (;;) {
            float SWM = wsumf(Ms, Me);
            if (a < nL) {
              float SYe = rSY[slotL + nL - 1 - a]; int ste = rST[slotL + nL - 1 - a];
              float SWe = wsumf(ste, Ms - 1);
              if (SYe * SWM <= SYM * SWe) { SYM += SYe; Ms = ste; ++a; continue; }
            }
            if (bb < nR) {
              float SYb = rSY[slotR + bb]; int sb = rST[slotR + bb];
              int eb = (bb + 1 < nR) ? (rST[slotR + bb + 1] - 1) : (gendR - 1);
              float SWb = wsumf(sb, eb);
              if (SYM * SWb <= SYb * SWM) { SYM += SYb; Me = eb; ++bb; continue; }
            }
            break;
          }
          rST[slotL + nL - a] = Ms; rSY[slotL + nL - a] = SYM;
        }
      }
      ca[p] = a; cb[p] = bb; cM[p] = hasM;
    }
    __syncthreads();
    {
      int wv = t >> 6, lane = t & 63;
      for (int p = wv; p < P; p += 4) {      // pairs disjoint -> waves in parallel
        int kL = p << (j + 1), kR = kL + (1 << j);
        int nL = lcnt[kL], nR = lcnt[kR];
        int a = ca[p], bb = cb[p], hasM = cM[p];
        int destBase = kL * PAD + nL - a + hasM;
        int srcBase = kR * PAD + bb;
        int ncopy = nR - bb;
        for (int off = 0; off < ncopy; off += 64) {  // wave-staged, dest<=src, in order
          int k2 = off + lane; bool act = k2 < ncopy;
          int vt = 0; float vs = 0.f;
          if (act) { vt = rST[srcBase + k2]; vs = rSY[srcBase + k2]; }
          if (act) { rST[destBase + k2] = vt; rSY[destBase + k2] = vs; }
        }
      }
    }
    __syncthreads();
    if (t < P) {
      int p = t; int kL = p << (j + 1), kR = kL + (1 << j);
      lcnt[kL] = lcnt[kL] - ca[p] + cM[p] + (lcnt[kR] - cb[p]);
    }
    __syncthreads();
  }
  // write region records (coalesced) + count
  int n = lcnt[0];
  for (int k = t; k < n; k += 256)
    REC[(size_t)b * REGSLOT + k] = make_int2(rST[k], __float_as_int(rSY[k]));
  if (t == 0) cnt2[b] = n;
}

// ---------- 4) fused merge + out: 512 blocks ----------
// Blocks 0-7: LDS-staged 8-way group merge. Block 0: final 8-way merge + per-block
// flag broadcast (1 poller per line). All blocks prefetch out data before polling.

__global__ __launch_bounds__(256) void merge_out_kernel(
    int2* __restrict__ REC, const int* __restrict__ cnt2,
    const u32* __restrict__ rstart, u64* __restrict__ grpf, u64* __restrict__ ownf,
    const u32* __restrict__ keyRaw, const u32* __restrict__ mm,
    const u32* __restrict__ cdf, float* __restrict__ out) {
  __shared__ int   mST[CAPL];
  __shared__ float mSY[CAPL];
  __shared__ int   sST[CAPS];
  __shared__ float sSY[CAPS];
  __shared__ u32 rs[65];
  __shared__ int gcnt[8];
  __shared__ int pcnt[8];
  __shared__ int shInt[4];
  int t = threadIdx.x, b = blockIdx.x;
  int i = b * 256 + t;

  int p_ = 0; float oexp = 0.0f;
  u32 kmin = mm[0], kmax = mm[1];
  float smax = key_to_score(kmin);
  u32 okey;
  bool inLds = false;
  int n = 0;

  if (b >= 8) {
    // prefetch out-phase data (overlaps the merge happening on blocks 0-7)
    okey = keyRaw[i];
    u32 g = bucket_of(okey, kmin, kmax);
    p_ = (int)cdf[g];
    oexp = fexp(key_to_score(okey) - smax);
  } else {
    // ---- group merge: regions b*8 .. b*8+7 ----
    if (t < 8) gcnt[t] = cnt2[b * 8 + t];
    if (t < 65) rs[t] = rstart[t];
    __syncthreads();
    int total8 = 0;
#pragma unroll
    for (int k = 0; k < 8; ++k) total8 += gcnt[k];
    n = gcnt[0];
    int slotL = (b * 8) * REGSLOT;
    if (total8 <= CAPL) {
      inLds = true;
      // stage left region into LDS
      for (int k2 = t; k2 < n; k2 += 256) {
        int2 r = REC[slotL + k2]; mST[k2] = r.x; mSY[k2] = __int_as_float(r.y);
      }
      __syncthreads();
      for (int k = 1; k < 8; ++k) {
        int nR = gcnt[k];
        int slotR = (b * 8 + k) * REGSLOT;
        for (int k2 = t; k2 < nR; k2 += 256) {
          int2 r = REC[slotR + k2]; sST[k2] = r.x; sSY[k2] = __int_as_float(r.y);
        }
        __syncthreads();
        if (t == 0) lds_cascade(mST, mSY, n, sST, sSY, nR,
                                (int)rs[b * 8 + k], (int)rs[b * 8 + k + 1], shInt);
        __syncthreads();
        int a = shInt[0], bb = shInt[1], hasM = shInt[2];
        int destBase = n - a + hasM;
        int ncopy = nR - bb;
        for (int k2 = t; k2 < ncopy; k2 += 256) {
          mST[destBase + k2] = sST[bb + k2]; mSY[destBase + k2] = sSY[bb + k2];
        }
        __syncthreads();
        n = destBase + ncopy;
      }
      // publish group stack (skip write for block 0: final merge reads LDS directly,
      // but blocks 1-7 must write for block 0's consumption)
      if (b != 0) {
        for (int k2 = t; k2 < n; k2 += 256)
          REC[slotL + k2] = make_int2(mST[k2], __float_as_int(mSY[k2]));
      }
    } else {
      // global fallback (rare)
      for (int k = 1; k < 8; ++k) {
        int nR = gcnt[k];
        int slotR = (b * 8 + k) * REGSLOT;
        n = merge_step(REC, slotL, n, slotR, nR,
                       (int)rs[b * 8 + k], (int)rs[b * 8 + k + 1], t, shInt);
      }
    }
    __syncthreads();
    if (b != 0) {
      if (t == 0) { __threadfence(); atomicExch(&grpf[(size_t)b * FPAD], (1ull << 32) | (u64)(u32)n); }
      // prefetch out data now (overlaps block 0's final merge)
      okey = keyRaw[i];
      u32 g = bucket_of(okey, kmin, kmax);
      p_ = (int)cdf[g];
      oexp = fexp(key_to_score(okey) - smax);
    } else {
      // ---- final 8-way merge of group stacks (block 0) ----
      if (t < 7) {
        u64 f;
        do { f = agent_ld(&grpf[(size_t)(1 + t) * FPAD]); } while ((u32)(f >> 32) == 0u);
        pcnt[1 + t] = (int)(u32)f;
      }
      __syncthreads();
      __threadfence();                       // acquire the 7 group stacks
      int totalF = n;
      for (int k = 1; k < 8; ++k) totalF += pcnt[k];
      if (totalF <= CAPL) {
        if (!inLds) {                        // own group went the global path: stage it
          for (int k2 = t; k2 < n; k2 += 256) {
            int2 r = REC[k2]; mST[k2] = r.x; mSY[k2] = __int_as_float(r.y);
          }
          __syncthreads();
          inLds = true;
        }
        for (int k = 1; k < 8; ++k) {
          int nR = pcnt[k];
          int slotR = (k * 8) * REGSLOT;
          for (int k2 = t; k2 < nR; k2 += 256) {
            int2 r = REC[slotR + k2]; sST[k2] = r.x; sSY[k2] = __int_as_float(r.y);
          }
          __syncthreads();
          if (t == 0) lds_cascade(mST, mSY, n, sST, sSY, nR,
                                  (int)rs[k * 8], (int)rs[k * 8 + 8], shInt);
          __syncthreads();
          int a = shInt[0], bb = shInt[1], hasM = shInt[2];
          int destBase = n - a + hasM;
          int ncopy = nR - bb;
          for (int k2 = t; k2 < ncopy; k2 += 256) {
            mST[destBase + k2] = sST[bb + k2]; mSY[destBase + k2] = sSY[bb + k2];
          }
          __syncthreads();
          n = destBase + ncopy;
        }
        // write final table for the other 511 blocks
        for (int k2 = t; k2 < n; k2 += 256)
          REC[k2] = make_int2(mST[k2], __float_as_int(mSY[k2]));
      } else {
        inLds = false;
        for (int k = 1; k < 8; ++k) {
          int nR = pcnt[k];
          int slotR = (k * 8) * REGSLOT;
          n = merge_step(REC, 0, n, slotR, nR,
                         (int)rs[k * 8], (int)rs[k * 8 + 8], t, shInt);
        }
      }
      __syncthreads();
      // broadcast root: 512 DISTINCT lines, one poller each (safe pattern)
      if (t == 0) __threadfence();
      __syncthreads();
      {
        u64 v = (1ull << 32) | (u64)(u32)n;
        for (int k2 = t; k2 < 512; k2 += 256) atomicExch(&ownf[(size_t)k2 * FPAD], v);
      }
      // prefetch out data
      okey = keyRaw[i];
      u32 g = bucket_of(okey, kmin, kmax);
      p_ = (int)cdf[g];
      oexp = fexp(key_to_score(okey) - smax);
    }
  }

  // ---- out phase ----
  int m;
  if (b == 0) {
    m = n;
  } else {
    if (t == 0) {
      u64 f;
      do {
        f = agent_ld(&ownf[(size_t)b * FPAD]);
        if ((f >> 32) == 0ull) __builtin_amdgcn_s_sleep(2);
      } while ((f >> 32) == 0ull);
      shInt[3] = (int)(u32)f;
    }
    __syncthreads();
    __threadfence();                         // acquire final REC
    m = shInt[3];
    inLds = false;
  }
  bool useL = (m <= CAPL);
  if (useL && !inLds) {
    for (int k = t; k < m; k += 256) {
      int2 r = REC[k];
      mST[k] = r.x; mSY[k] = __int_as_float(r.y);
    }
  }
  __syncthreads();
  int lo = 0, hi = m - 1;
  if (useL) {
    while (lo < hi) {
      int mid = (lo + hi + 1) >> 1;
      if (mST[mid] <= p_) lo = mid; else hi = mid - 1;
    }
    int s0 = mST[lo];
    int e0 = (lo + 1 < m) ? (mST[lo + 1] - 1) : (N_ITEMS - 1);
    float SW = wsumf(s0, e0);
    float rank = oexp * SW / mSY[lo];
    out[i] = floorf(rank * (1.0f / 3.0f)) + 1.0f;
  } else {
    while (lo < hi) {
      int mid = (lo + hi + 1) >> 1;
      if (REC[mid].x <= p_) lo = mid; else hi = mid - 1;
    }
    int2 r = REC[lo];
    int s0 = r.x;
    int e0 = (lo + 1 < m) ? (REC[lo + 1].x - 1) : (N_ITEMS - 1);
    float SW = wsumf(s0, e0);
    float rank = oexp * SW / recSY(r);
    out[i] = floorf(rank * (1.0f / 3.0f)) + 1.0f;
  }
}

// ---------- launch ----------

extern "C" void kernel_launch(void* const* d_in, const int* in_sizes, int n_in,
                              void* d_out, int out_size, void* d_ws, size_t ws_size,
                              hipStream_t stream) {
  const float* x  = (const float*)d_in[0];
  const float* w1 = (const float*)d_in[1];
  const float* b1 = (const float*)d_in[2];
  const float* w2 = (const float*)d_in[3];
  const float* b2 = (const float*)d_in[4];
  float* out = (float*)d_out;

  char* ws = (char*)d_ws;
  size_t o = 0;
  u32* mm     = (u32*)(ws + o); o += 64;
  u32* pmin   = (u32*)(ws + o); o += (size_t)512 * 4;
  u32* pmax   = (u32*)(ws + o); o += (size_t)512 * 4;
  u32* cdf    = (u32*)(ws + o); o += (size_t)(NB + 4) * 4;
  u32* rstart = (u32*)(ws + o); o += (size_t)(MBLK + 4) * 4;
  u32* keyRaw = (u32*)(ws + o); o += (size_t)N_ITEMS * 4;
  int2* REC   = (int2*)(ws + o); o += (size_t)N_ITEMS * 8;
  int* cnt2   = (int*)(ws + o);  o += (size_t)MBLK * 4;
  u64* hist8  = (u64*)(ws + o); o += (size_t)NSLICE * NB * 8;    // 4 MB, zeroed in k1
  u64* flags  = (u64*)(ws + o); o += (size_t)MBLK * FPAD * 8;    // zeroed in k1
  u64* grpf   = (u64*)(ws + o); o += (size_t)8 * FPAD * 8;       // zeroed in k1
  u64* ownf   = (u64*)(ws + o); o += (size_t)512 * FPAD * 8;     // zeroed in k1

  score_key_kernel<<<512, 256, 0, stream>>>(x, w1, b1, w2, b2, keyRaw,
                                            pmin, pmax, hist8, flags, grpf, ownf);
  hist_kernel<<<512, 256, 0, stream>>>(keyRaw, pmin, pmax, hist8, mm);
  scan_pav_kernel<<<MBLK, 256, 0, stream>>>(hist8, flags, cdf, REC, cnt2, rstart);
  merge_out_kernel<<<512, 256, 0, stream>>>(REC, cnt2, rstart, grpf, ownf,
                                            keyRaw, mm, cdf, out);
}

// Round 7
// 128.941 us; speedup vs baseline: 1.1506x; 1.1506x over previous
//
#include <hip/hip_runtime.h>
#include <stdint.h>

typedef unsigned int u32;
typedef unsigned long long u64;

#define N_ITEMS 131072
#define NB 131072                   // buckets (monotone in descending score)
#define MBLK 64                     // solver blocks
#define BUCK_PER_BLK 2048           // buckets per solver block
#define CH_PER_BLK 32               // chunks (64 buckets) per solver block
#define PAD 65                      // padded LDS record stride per chunk
#define REGSLOT 2048                // record slots per region in global REC
#define FPAD 16                     // u64s per flag slot -> 128B (own cacheline)
#define CAPM 4096                   // LDS merge stack capacity (records)
#define CAPO 4096                   // out kernel LDS table capacity
#define FIXSCALE 268435456.0f       // 2^28 fixed-point scale for sum(exp)
#define FIXMASK ((1ull << 46) - 1)

// ---------- helpers ----------

// sum_{i=s}^{e} (N - i) — exact weight-side sum of exp(w) over sorted positions
__device__ __forceinline__ float wsumf(int s, int e) {
  return 0.5f * (float)(e - s + 1) * (float)(2 * N_ITEMS - s - e);
}

__device__ __forceinline__ float key_to_score(u32 key) {
  u32 m = ~key;
  u32 u = (m & 0x80000000u) ? (m ^ 0x80000000u) : ~m;
  return __uint_as_float(u);
}

#define LOG2E 1.4426950408889634f
__device__ __forceinline__ float fexp(float x) { return exp2f(x * LOG2E); }

// ascending key == descending score; ascending bucket == descending score
__device__ __forceinline__ u32 bucket_of(u32 key, u32 kmin, u32 kmax) {
  double scale = (double)NB / ((double)(kmax - kmin) + 1.0);
  u32 b = (u32)((double)(key - kmin) * scale);
  return b < NB ? b : (NB - 1);
}

__device__ __forceinline__ float recSY(int2 r) { return __int_as_float(r.y); }

// relaxed agent-scope load: polls WITHOUT taking exclusive line ownership
__device__ __forceinline__ u64 agent_ld(const u64* p) {
  return __hip_atomic_load(p, __ATOMIC_RELAXED, __HIP_MEMORY_SCOPE_AGENT);
}

// ---- GLOBAL-memory pairwise region merge (fallback path; measured-correct) ----
__device__ int merge_step(int2* __restrict__ REC, int slotL, int nL,
                          int slotR, int nR, int gstartR, int gendR,
                          int t, int* shInt) {
  if (t == 0) {
    int a = 0, bb = 0, hasM = 0;
    if (nL > 0 && nR > 0) {
      int2 rL = REC[slotL + nL - 1];
      float SYL = recSY(rL); int stL = rL.x;
      int2 rR = REC[slotR];
      float SYR = recSY(rR);
      int eR = (nR > 1) ? (REC[slotR + 1].x - 1) : (gendR - 1);
      float SWL = wsumf(stL, gstartR - 1);
      float SWR = wsumf(gstartR, eR);
      if (SYL * SWR <= SYR * SWL) {
        hasM = 1;
        float SYM = SYL + SYR; int Ms = stL, Me = eR;
        a = 1; bb = 1;
        for (;;) {
          float SWM = wsumf(Ms, Me);
          if (a < nL) {
            int2 re = REC[slotL + nL - 1 - a];
            float SYe = recSY(re); int ste = re.x;
            float SWe = wsumf(ste, Ms - 1);
            if (SYe * SWM <= SYM * SWe) { SYM += SYe; Ms = ste; ++a; continue; }
          }
          if (bb < nR) {
            int2 rb = REC[slotR + bb];
            float SYb = recSY(rb); int sb = rb.x;
            int eb = (bb + 1 < nR) ? (REC[slotR + bb + 1].x - 1) : (gendR - 1);
            float SWb = wsumf(sb, eb);
            if (SYM * SWb <= SYb * SWM) { SYM += SYb; Me = eb; ++bb; continue; }
          }
          break;
        }
        REC[slotL + nL - a] = make_int2(Ms, __float_as_int(SYM));
      }
    }
    shInt[0] = a; shInt[1] = bb; shInt[2] = hasM;
  }
  __syncthreads();
  int a = shInt[0], bb = shInt[1], hasM = shInt[2];
  int destBase = slotL + nL - a + hasM;
  int srcBase = slotR + bb;
  int ncopy = nR - bb;
  if (destBase != srcBase) {
    for (int off = 0; off < ncopy; off += 2048) {
      int2 v[8];
#pragma unroll
      for (int j = 0; j < 8; ++j) {
        int k2 = off + j * 256 + t;
        if (k2 < ncopy) v[j] = REC[srcBase + k2];
      }
      __syncthreads();
#pragma unroll
      for (int j = 0; j < 8; ++j) {
        int k2 = off + j * 256 + t;
        if (k2 < ncopy) REC[destBase + k2] = v[j];
      }
      __syncthreads();
    }
  }
  __syncthreads();
  return nL - a + hasM + ncopy;
}

// ---- LDS cascade walk (t0 only): left stack mST/mSY[0..n), incoming sST/sSY[0..nR) ----
__device__ void lds_cascade(int* mST, float* mSY, int n,
                            const int* sST, const float* sSY, int nR,
                            int gstartR, int gendR, int* shInt) {
  int a = 0, bb = 0, hasM = 0;
  if (n > 0 && nR > 0) {
    float SYL = mSY[n - 1]; int stL = mST[n - 1];
    float SYR = sSY[0];
    int eR = (nR > 1) ? (sST[1] - 1) : (gendR - 1);
    float SWL = wsumf(stL, gstartR - 1);
    float SWR = wsumf(gstartR, eR);
    if (SYL * SWR <= SYR * SWL) {
      hasM = 1;
      float SYM = SYL + SYR; int Ms = stL, Me = eR;
      a = 1; bb = 1;
      for (;;) {
        float SWM = wsumf(Ms, Me);
        if (a < n) {
          float SYe = mSY[n - 1 - a]; int ste = mST[n - 1 - a];
          float SWe = wsumf(ste, Ms - 1);
          if (SYe * SWM <= SYM * SWe) { SYM += SYe; Ms = ste; ++a; continue; }
        }
        if (bb < nR) {
          float SYb = sSY[bb]; int sb = sST[bb];
          int eb = (bb + 1 < nR) ? (sST[bb + 1] - 1) : (gendR - 1);
          float SWb = wsumf(sb, eb);
          if (SYM * SWb <= SYb * SWM) { SYM += SYb; Me = eb; ++bb; continue; }
        }
        break;
      }
      mST[n - a] = Ms; mSY[n - a] = SYM;
    }
  }
  shInt[0] = a; shInt[1] = bb; shInt[2] = hasM;
}

// ---------- 1) scores -> keys; per-block minmax; zero hist/flags ----------

__global__ __launch_bounds__(256) void score_key_kernel(
    const float* __restrict__ x,
    const float* __restrict__ w1, const float* __restrict__ b1,
    const float* __restrict__ w2, const float* __restrict__ b2,
    u32* __restrict__ keyRaw, u32* __restrict__ pmin, u32* __restrict__ pmax,
    u64* __restrict__ hist, u64* __restrict__ flags, u64* __restrict__ grpf) {
  __shared__ u32 wmn[4], wmx[4];
  int t = threadIdx.x;
  int i = blockIdx.x * 256 + t;
  // zero the 1 MB histogram (one uint2 per thread, coalesced)
  ((uint2*)hist)[i] = make_uint2(0u, 0u);
  if (i < MBLK) flags[(size_t)i * FPAD] = 0ull;
  if (i < 8) grpf[(size_t)i * FPAD] = 0ull;
  float xv = x[i];
  float s = b2[0];
#pragma unroll
  for (int j = 0; j < 32; ++j) {
    float h = fmaf(xv, w1[j], b1[j]);
    h = fmaxf(h, 0.0f);
    s = fmaf(h, w2[j], s);
  }
  u32 u = __float_as_uint(s);
  u32 m = u ^ ((u & 0x80000000u) ? 0xFFFFFFFFu : 0x80000000u); // ascending map
  u32 key = ~m;
  keyRaw[i] = key;
  u32 mn = key, mx = key;
#pragma unroll
  for (int off = 32; off > 0; off >>= 1) {
    mn = min(mn, (u32)__shfl_xor((int)mn, off));
    mx = max(mx, (u32)__shfl_xor((int)mx, off));
  }
  if ((t & 63) == 0) { wmn[t >> 6] = mn; wmx[t >> 6] = mx; }
  __syncthreads();
  if (t == 0) {
    mn = min(min(wmn[0], wmn[1]), min(wmn[2], wmn[3]));
    mx = max(max(wmx[0], wmx[1]), max(wmx[2], wmx[3]));
    pmin[blockIdx.x] = mn;
    pmax[blockIdx.x] = mx;
  }
}

// ---------- 2) bucket aggregates: ONE packed u64 atomic per item ----------
// bits [46:63] = count, bits [0:45] = fixed-point (2^28) sum of exp(s - smax)

__global__ __launch_bounds__(256) void hist_kernel(
    const u32* __restrict__ keyRaw,
    const u32* __restrict__ pmin, const u32* __restrict__ pmax,
    u64* __restrict__ hist, u32* __restrict__ mm) {
  __shared__ u32 s0[256], s1[256];
  int t = threadIdx.x;
  s0[t] = min(pmin[t], pmin[t + 256]);
  s1[t] = max(pmax[t], pmax[t + 256]);
  __syncthreads();
  for (int off = 128; off > 0; off >>= 1) {
    if (t < off) { s0[t] = min(s0[t], s0[t + off]); s1[t] = max(s1[t], s1[t + off]); }
    __syncthreads();
  }
  u32 kmin = s0[0], kmax = s1[0];
  if (blockIdx.x == 0 && t == 0) { mm[0] = kmin; mm[1] = kmax; }
  int i = blockIdx.x * 256 + t;
  u32 key = keyRaw[i];
  u32 g = bucket_of(key, kmin, kmax);
  float smax = key_to_score(kmin);
  float v = fexp(key_to_score(key) - smax);            // in (0, 1]
  u64 fix = (u64)fmaxf(1.0f, fmaf(v, FIXSCALE, 0.5f)); // clamp: SY can never be 0
  atomicAdd(&hist[g], (1ull << 46) | fix);             // peak bucket ~4: L2 combines
}

// ---------- 3) scan + PAV + in-LDS merges -> 64 region stacks ----------

__global__ __launch_bounds__(256) void scan_pav_kernel(
    const u64* __restrict__ hist, u64* __restrict__ flags,
    u32* __restrict__ cdf, int2* __restrict__ REC,
    int* __restrict__ cnt2, u32* __restrict__ rstart) {
  __shared__ u32 vals[BUCK_PER_BLK + 1];   // counts -> global-exclusive cdf
  __shared__ float seL[BUCK_PER_BLK];
  __shared__ int   rST[CH_PER_BLK * PAD];
  __shared__ float rSY[CH_PER_BLK * PAD];
  __shared__ u32 wsum[4];
  __shared__ u32 regS[65];
  __shared__ int lcnt[CH_PER_BLK];
  __shared__ int ca[16], cb[16], cM[16];
  int t = threadIdx.x, b = blockIdx.x;
  int B0 = b * BUCK_PER_BLK;
  // coalesced load (single slice)
  for (int q = 0; q < 8; ++q) {
    int ii = q * 256 + t;
    u64 acc = hist[(size_t)B0 + ii];
    vals[ii] = (u32)(acc >> 46);
    seL[ii] = (float)(acc & FIXMASK) * (1.0f / FIXSCALE);
  }
  __syncthreads();
  // per-thread local prefix over contiguous 8, then wave shfl scan + 4-wave combine
  u32 loc[8]; u32 s = 0;
  for (int q = 0; q < 8; ++q) { loc[q] = s; s += vals[t * 8 + q]; }
  u32 inc = s;
#pragma unroll
  for (int off = 1; off < 64; off <<= 1) {
    u32 o2 = (u32)__shfl_up((int)inc, off);
    if ((t & 63) >= off) inc += o2;
  }
  if ((t & 63) == 63) wsum[t >> 6] = inc;
  __syncthreads();
  u32 w = (u32)(t >> 6);
  u32 woff = 0;
  if (w > 0) woff += wsum[0];
  if (w > 1) woff += wsum[1];
  if (w > 2) woff += wsum[2];
  u32 total = wsum[0] + wsum[1] + wsum[2] + wsum[3];
  u32 texcl = woff + inc - s;
  // publish aggregate; wait-all over 64 blocks (64 distinct lines, 64 pollers: safe)
  if (t == 0) atomicExch(&flags[(size_t)b * FPAD], (1ull << 32) | (u64)total);
  if (t < 64) {
    u64 f;
    do { f = agent_ld(&flags[(size_t)t * FPAD]); } while ((u32)(f >> 32) == 0u);
    u32 v = (u32)f, inc2 = v;
#pragma unroll
    for (int off = 1; off < 64; off <<= 1) {
      u32 o2 = (u32)__shfl_up((int)inc2, off);
      if (t >= off) inc2 += o2;
    }
    regS[t] = inc2 - v;
    if (t == 63) regS[64] = inc2;          // == N_ITEMS
  }
  __syncthreads();
  u32 exclu = regS[b];
  u32 tbase = texcl + exclu;
  // overwrite vals with GLOBAL exclusive cdf; mirror to global (vectorized)
  u32 eb8[8];
  for (int q = 0; q < 8; ++q) { eb8[q] = tbase + loc[q]; vals[t * 8 + q] = eb8[q]; }
  {
    uint4* c4 = (uint4*)(cdf + B0 + t * 8);
    c4[0] = make_uint4(eb8[0], eb8[1], eb8[2], eb8[3]);
    c4[1] = make_uint4(eb8[4], eb8[5], eb8[6], eb8[7]);
  }
  if (t == 255) vals[BUCK_PER_BLK] = exclu + total;
  if (b == 0 && t < 65) rstart[t] = regS[t];
  __syncthreads();
  // per-chunk PAV (32 threads), stack stored in place at padded stride
  if (t < CH_PER_BLK) {
    int base = t * PAD;
    int ptr = 0; bool have = false;
    float syT = 0.0f; int stT = 0;
    for (int k = 0; k < 64; ++k) {
      u32 cs = vals[t * 64 + k], ce = vals[t * 64 + k + 1];
      if (ce == cs) continue;                 // empty bucket
      float syC = seL[t * 64 + k];
      int stC = (int)cs, eC = (int)ce - 1;
      while (have) {
        float SWc = wsumf(stC, eC);
        float SWt = wsumf(stT, stC - 1);
        if (!(syT * SWc <= syC * SWt)) break; // merge while val_top <= val_cur
        syC += syT; stC = stT;
        if (ptr == 0) { have = false; break; }
        --ptr;
        stT = rST[base + ptr]; syT = rSY[base + ptr];
      }
      if (have) { rST[base + ptr] = stT; rSY[base + ptr] = syT; ++ptr; }
      stT = stC; syT = syC; have = true;
    }
    if (have) { rST[base + ptr] = stT; rSY[base + ptr] = syT; ++ptr; }
    lcnt[t] = ptr;
  }
  __syncthreads();
  // merge levels 0..4 entirely in LDS; copies wave-parallel across disjoint pairs
  for (int j = 0; j < 5; ++j) {
    int P = CH_PER_BLK >> (j + 1);
    if (t < P) {
      int p = t;
      int kL = p << (j + 1), kR = kL + (1 << j);
      int slotL = kL * PAD, slotR = kR * PAD;
      int nL = lcnt[kL], nR = lcnt[kR];
      int a = 0, bb = 0, hasM = 0;
      if (nL > 0 && nR > 0) {
        int gstartR = (int)vals[kR * 64];
        int gendR   = (int)vals[(kR + (1 << j)) * 64];
        float SYL = rSY[slotL + nL - 1]; int stL = rST[slotL + nL - 1];
        float SYR = rSY[slotR];
        int eR = (nR > 1) ? (rST[slotR + 1] - 1) : (gendR - 1);
        float SWL = wsumf(stL, gstartR - 1);
        float SWR = wsumf(gstartR, eR);
        if (SYL * SWR <= SYR * SWL) {
          hasM = 1;
          float SYM = SYL + SYR; int Ms = stL, Me = eR;
          a = 1; bb = 1;
          for (;;) {
            float SWM = wsumf(Ms, Me);
            if (a < nL) {
              float SYe = rSY[slotL + nL - 1 - a]; int ste = rST[slotL + nL - 1 - a];
              float SWe = wsumf(ste, Ms - 1);
              if (SYe * SWM <= SYM * SWe) { SYM += SYe; Ms = ste; ++a; continue; }
            }
            if (bb < nR) {
              float SYb = rSY[slotR + bb]; int sb = rST[slotR + bb];
              int eb = (bb + 1 < nR) ? (rST[slotR + bb + 1] - 1) : (gendR - 1);
              float SWb = wsumf(sb, eb);
              if (SYM * SWb <= SYb * SWM) { SYM += SYb; Me = eb; ++bb; continue; }
            }
            break;
          }
          rST[slotL + nL - a] = Ms; rSY[slotL + nL - a] = SYM;
        }
      }
      ca[p] = a; cb[p] = bb; cM[p] = hasM;
    }
    __syncthreads();
    {
      int wv = t >> 6, lane = t & 63;
      for (int p = wv; p < P; p += 4) {      // pairs disjoint -> waves in parallel
        int kL = p << (j + 1), kR = kL + (1 << j);
        int nL = lcnt[kL], nR = lcnt[kR];
        int a = ca[p], bb = cb[p], hasM = cM[p];
        int destBase = kL * PAD + nL - a + hasM;
        int srcBase = kR * PAD + bb;
        int ncopy = nR - bb;
        for (int off = 0; off < ncopy; off += 64) {  // wave-staged, dest<=src, in order
          int k2 = off + lane; bool act = k2 < ncopy;
          int vt = 0; float vs = 0.f;
          if (act) { vt = rST[srcBase + k2]; vs = rSY[srcBase + k2]; }
          if (act) { rST[destBase + k2] = vt; rSY[destBase + k2] = vs; }
        }
      }
    }
    __syncthreads();
    if (t < P) {
      int p = t; int kL = p << (j + 1), kR = kL + (1 << j);
      lcnt[kL] = lcnt[kL] - ca[p] + cM[p] + (lcnt[kR] - cb[p]);
    }
    __syncthreads();
  }
  // write region records (coalesced) + count
  int n = lcnt[0];
  for (int k = t; k < n; k += 256)
    REC[(size_t)b * REGSLOT + k] = make_int2(rST[k], __float_as_int(rSY[k]));
  if (t == 0) cnt2[b] = n;
}

// ---------- 4) merge kernel: 8 blocks, LDS-staged cascades; block 0 finishes ----------

__global__ __launch_bounds__(256) void merge_kernel(
    int2* __restrict__ REC, int* __restrict__ cnt2,
    const u32* __restrict__ rstart, u64* __restrict__ grpf) {
  __shared__ int   mST[CAPM];
  __shared__ float mSY[CAPM];
  __shared__ int   sST[CAPM];
  __shared__ float sSY[CAPM];
  __shared__ u32 rs[65];
  __shared__ int gcnt[8];
  __shared__ int pcnt[8];
  __shared__ int shInt[4];
  int t = threadIdx.x, b = blockIdx.x;
  if (t < 8) gcnt[t] = cnt2[b * 8 + t];
  if (t < 65) rs[t] = rstart[t];
  __syncthreads();
  int total8 = 0;
#pragma unroll
  for (int k = 0; k < 8; ++k) total8 += gcnt[k];
  int n = gcnt[0];
  int slotL = (b * 8) * REGSLOT;
  bool inLds = (total8 <= CAPM);
  if (inLds) {
    // stage left region, then merge the other 7 via LDS cascades (walks ~25cy not ~300cy)
    for (int k2 = t; k2 < n; k2 += 256) {
      int2 r = REC[slotL + k2]; mST[k2] = r.x; mSY[k2] = __int_as_float(r.y);
    }
    __syncthreads();
    for (int k = 1; k < 8; ++k) {
      int nR = gcnt[k];
      int slotR = (b * 8 + k) * REGSLOT;
      for (int k2 = t; k2 < nR; k2 += 256) {
        int2 r = REC[slotR + k2]; sST[k2] = r.x; sSY[k2] = __int_as_float(r.y);
      }
      __syncthreads();
      if (t == 0) lds_cascade(mST, mSY, n, sST, sSY, nR,
                              (int)rs[b * 8 + k], (int)rs[b * 8 + k + 1], shInt);
      __syncthreads();
      int a = shInt[0], bb = shInt[1], hasM = shInt[2];
      int destBase = n - a + hasM;
      int ncopy = nR - bb;
      for (int k2 = t; k2 < ncopy; k2 += 256) {
        mST[destBase + k2] = sST[bb + k2]; mSY[destBase + k2] = sSY[bb + k2];
      }
      __syncthreads();
      n = destBase + ncopy;
    }
    // ALWAYS write the group stack back (incl. b==0: final merge may take global path)
    for (int k2 = t; k2 < n; k2 += 256)
      REC[slotL + k2] = make_int2(mST[k2], __float_as_int(mSY[k2]));
    __syncthreads();
  } else {
    for (int k = 1; k < 8; ++k) {
      int nR = gcnt[k];
      int slotR = (b * 8 + k) * REGSLOT;
      n = merge_step(REC, slotL, n, slotR, nR,
                     (int)rs[b * 8 + k], (int)rs[b * 8 + k + 1], t, shInt);
    }
  }
  if (t == 0) { __threadfence(); atomicExch(&grpf[(size_t)b * FPAD], (1ull << 32) | (u64)(u32)n); }
  if (b == 0) {
    // 7 distinct lines, one poller each: safe pattern
    if (t < 7) {
      u64 f;
      do { f = agent_ld(&grpf[(size_t)(1 + t) * FPAD]); } while ((u32)(f >> 32) == 0u);
      pcnt[1 + t] = (int)(u32)f;
    }
    __syncthreads();
    __threadfence();                       // acquire the 7 group stacks
    int totalF = n;
    for (int k = 1; k < 8; ++k) totalF += pcnt[k];
    if (totalF <= CAPM) {                  // totalF bounds every nR: sST fits
      if (!inLds) {
        for (int k2 = t; k2 < n; k2 += 256) {
          int2 r = REC[k2]; mST[k2] = r.x; mSY[k2] = __int_as_float(r.y);
        }
        __syncthreads();
      }
      for (int k = 1; k < 8; ++k) {
        int nR = pcnt[k];
        int slotR = (k * 8) * REGSLOT;
        for (int k2 = t; k2 < nR; k2 += 256) {
          int2 r = REC[slotR + k2]; sST[k2] = r.x; sSY[k2] = __int_as_float(r.y);
        }
        __syncthreads();
        if (t == 0) lds_cascade(mST, mSY, n, sST, sSY, nR,
                                (int)rs[k * 8], (int)rs[k * 8 + 8], shInt);
        __syncthreads();
        int a = shInt[0], bb = shInt[1], hasM = shInt[2];
        int destBase = n - a + hasM;
        int ncopy = nR - bb;
        for (int k2 = t; k2 < ncopy; k2 += 256) {
          mST[destBase + k2] = sST[bb + k2]; mSY[destBase + k2] = sSY[bb + k2];
        }
        __syncthreads();
        n = destBase + ncopy;
      }
      for (int k2 = t; k2 < n; k2 += 256)
        REC[k2] = make_int2(mST[k2], __float_as_int(mSY[k2]));
    } else {
      for (int k = 1; k < 8; ++k) {
        int nR = pcnt[k];
        int slotR = (k * 8) * REGSLOT;
        n = merge_step(REC, 0, n, slotR, nR,
                       (int)rs[k * 8], (int)rs[k * 8 + 8], t, shInt);
      }
    }
    if (t == 0) cnt2[0] = n;               // kernel boundary publishes to out_kernel
  }
}

// ---------- 5) ranks + transform; LDS-staged search table; coalesced output ----------

__global__ __launch_bounds__(256) void out_kernel(
    const u32* __restrict__ keyRaw, const u32* __restrict__ mm,
    const u32* __restrict__ cdf, const int2* __restrict__ REC,
    const int* __restrict__ cnt2, float* __restrict__ out) {
  __shared__ int   rST[CAPO];
  __shared__ float rSY[CAPO];
  int t = threadIdx.x;
  int i = blockIdx.x * 256 + t;
  int m = cnt2[0];
  u32 kmin = mm[0], kmax = mm[1];
  u32 key = keyRaw[i];
  float smax = key_to_score(kmin);
  u32 g = bucket_of(key, kmin, kmax);
  int p = (int)cdf[g];               // block is bucket-aligned: position of bucket start
  bool useL = (m <= CAPO);
  if (useL) {
    for (int k = t; k < m; k += 256) {
      int2 r = REC[k];
      rST[k] = r.x; rSY[k] = __int_as_float(r.y);
    }
  }
  __syncthreads();
  int lo = 0, hi = m - 1;
  if (useL) {
    while (lo < hi) {
      int mid = (lo + hi + 1) >> 1;
      if (rST[mid] <= p) lo = mid; else hi = mid - 1;
    }
    int s0 = rST[lo];
    int e0 = (lo + 1 < m) ? (rST[lo + 1] - 1) : (N_ITEMS - 1);
    float SW = wsumf(s0, e0);
    float rank = fexp(key_to_score(key) - smax) * SW / rSY[lo];
    out[i] = floorf(rank * (1.0f / 3.0f)) + 1.0f;
  } else {
    while (lo < hi) {
      int mid = (lo + hi + 1) >> 1;
      if (REC[mid].x <= p) lo = mid; else hi = mid - 1;
    }
    int2 r = REC[lo];
    int s0 = r.x;
    int e0 = (lo + 1 < m) ? (REC[lo + 1].x - 1) : (N_ITEMS - 1);
    float SW = wsumf(s0, e0);
    float rank = fexp(key_to_score(key) - smax) * SW / recSY(r);
    out[i] = floorf(rank * (1.0f / 3.0f)) + 1.0f;
  }
}

// ---------- launch ----------

extern "C" void kernel_launch(void* const* d_in, const int* in_sizes, int n_in,
                              void* d_out, int out_size, void* d_ws, size_t ws_size,
                              hipStream_t stream) {
  const float* x  = (const float*)d_in[0];
  const float* w1 = (const float*)d_in[1];
  const float* b1 = (const float*)d_in[2];
  const float* w2 = (const float*)d_in[3];
  const float* b2 = (const float*)d_in[4];
  float* out = (float*)d_out;

  char* ws = (char*)d_ws;
  size_t o = 0;
  u32* mm     = (u32*)(ws + o); o += 64;
  u32* pmin   = (u32*)(ws + o); o += (size_t)512 * 4;
  u32* pmax   = (u32*)(ws + o); o += (size_t)512 * 4;
  u32* cdf    = (u32*)(ws + o); o += (size_t)(NB + 4) * 4;
  u32* rstart = (u32*)(ws + o); o += (size_t)(MBLK + 4) * 4;
  u32* keyRaw = (u32*)(ws + o); o += (size_t)N_ITEMS * 4;
  int2* REC   = (int2*)(ws + o); o += (size_t)N_ITEMS * 8;
  int* cnt2   = (int*)(ws + o);  o += (size_t)MBLK * 4;
  u64* hist   = (u64*)(ws + o); o += (size_t)NB * 8;             // 1 MB, zeroed in k1
  u64* flags  = (u64*)(ws + o); o += (size_t)MBLK * FPAD * 8;    // zeroed in k1
  u64* grpf   = (u64*)(ws + o); o += (size_t)8 * FPAD * 8;       // zeroed in k1

  score_key_kernel<<<512, 256, 0, stream>>>(x, w1, b1, w2, b2, keyRaw,
                                            pmin, pmax, hist, flags, grpf);
  hist_kernel<<<512, 256, 0, stream>>>(keyRaw, pmin, pmax, hist, mm);
  scan_pav_kernel<<<MBLK, 256, 0, stream>>>(hist, flags, cdf, REC, cnt2, rstart);
  merge_kernel<<<8, 256, 0, stream>>>(REC, cnt2, rstart, grpf);
  out_kernel<<<512, 256, 0, stream>>>(keyRaw, mm, cdf, REC, cnt2, out);
}

// Round 8
// 116.557 us; speedup vs baseline: 1.2729x; 1.1062x over previous
//
#include <hip/hip_runtime.h>
#include <stdint.h>

typedef unsigned int u32;
typedef unsigned long long u64;

#define N_ITEMS 131072
#define NB 131072                   // buckets (monotone in descending score)
#define NSLICE 4                    // XCD-sliced histogram copies (R7 showed slicing matters)
#define MBLK 64                     // solver blocks
#define BUCK_PER_BLK 2048           // buckets per solver block
#define CH_PER_BLK 32               // chunks (64 buckets) per solver block
#define PAD 65                      // padded LDS record stride per chunk
#define REGSLOT 2048                // record slots per region in global REC
#define FPAD 16                     // u64s per flag slot -> 128B (own cacheline)
#define CAPO 4096                   // out kernel LDS table capacity
#define FIXSCALE 268435456.0f       // 2^28 fixed-point scale for sum(exp)
#define FIXMASK ((1ull << 46) - 1)

// ---------- helpers ----------

// sum_{i=s}^{e} (N - i) — exact weight-side sum of exp(w) over sorted positions
__device__ __forceinline__ float wsumf(int s, int e) {
  return 0.5f * (float)(e - s + 1) * (float)(2 * N_ITEMS - s - e);
}

__device__ __forceinline__ float key_to_score(u32 key) {
  u32 m = ~key;
  u32 u = (m & 0x80000000u) ? (m ^ 0x80000000u) : ~m;
  return __uint_as_float(u);
}

#define LOG2E 1.4426950408889634f
__device__ __forceinline__ float fexp(float x) { return exp2f(x * LOG2E); }

// ascending key == descending score; ascending bucket == descending score
__device__ __forceinline__ u32 bucket_of(u32 key, u32 kmin, u32 kmax) {
  double scale = (double)NB / ((double)(kmax - kmin) + 1.0);
  u32 b = (u32)((double)(key - kmin) * scale);
  return b < NB ? b : (NB - 1);
}

__device__ __forceinline__ float recSY(int2 r) { return __int_as_float(r.y); }

// relaxed agent-scope load: polls WITHOUT taking exclusive line ownership
__device__ __forceinline__ u64 agent_ld(const u64* p) {
  return __hip_atomic_load(p, __ATOMIC_RELAXED, __HIP_MEMORY_SCOPE_AGENT);
}

// ---- GLOBAL-memory pairwise region merge (measured-correct, R5-proven) ----
__device__ int merge_step(int2* __restrict__ REC, int slotL, int nL,
                          int slotR, int nR, int gstartR, int gendR,
                          int t, int* shInt) {
  if (t == 0) {
    int a = 0, bb = 0, hasM = 0;
    if (nL > 0 && nR > 0) {
      int2 rL = REC[slotL + nL - 1];
      float SYL = recSY(rL); int stL = rL.x;
      int2 rR = REC[slotR];
      float SYR = recSY(rR);
      int eR = (nR > 1) ? (REC[slotR + 1].x - 1) : (gendR - 1);
      float SWL = wsumf(stL, gstartR - 1);
      float SWR = wsumf(gstartR, eR);
      if (SYL * SWR <= SYR * SWL) {
        hasM = 1;
        float SYM = SYL + SYR; int Ms = stL, Me = eR;
        a = 1; bb = 1;
        for (;;) {
          float SWM = wsumf(Ms, Me);
          if (a < nL) {
            int2 re = REC[slotL + nL - 1 - a];
            float SYe = recSY(re); int ste = re.x;
            float SWe = wsumf(ste, Ms - 1);
            if (SYe * SWM <= SYM * SWe) { SYM += SYe; Ms = ste; ++a; continue; }
          }
          if (bb < nR) {
            int2 rb = REC[slotR + bb];
            float SYb = recSY(rb); int sb = rb.x;
            int eb = (bb + 1 < nR) ? (REC[slotR + bb + 1].x - 1) : (gendR - 1);
            float SWb = wsumf(sb, eb);
            if (SYM * SWb <= SYb * SWM) { SYM += SYb; Me = eb; ++bb; continue; }
          }
          break;
        }
        REC[slotL + nL - a] = make_int2(Ms, __float_as_int(SYM));
      }
    }
    shInt[0] = a; shInt[1] = bb; shInt[2] = hasM;
  }
  __syncthreads();
  int a = shInt[0], bb = shInt[1], hasM = shInt[2];
  int destBase = slotL + nL - a + hasM;
  int srcBase = slotR + bb;
  int ncopy = nR - bb;
  if (destBase != srcBase) {
    for (int off = 0; off < ncopy; off += 2048) {
      int2 v[8];
#pragma unroll
      for (int j = 0; j < 8; ++j) {
        int k2 = off + j * 256 + t;
        if (k2 < ncopy) v[j] = REC[srcBase + k2];
      }
      __syncthreads();
#pragma unroll
      for (int j = 0; j < 8; ++j) {
        int k2 = off + j * 256 + t;
        if (k2 < ncopy) REC[destBase + k2] = v[j];
      }
      __syncthreads();
    }
  }
  __syncthreads();
  return nL - a + hasM + ncopy;
}

// ---------- 1) scores -> keys; per-block minmax; zero hist/flags ----------

__global__ __launch_bounds__(256) void score_key_kernel(
    const float* __restrict__ x,
    const float* __restrict__ w1, const float* __restrict__ b1,
    const float* __restrict__ w2, const float* __restrict__ b2,
    u32* __restrict__ keyRaw, u32* __restrict__ pmin, u32* __restrict__ pmax,
    u64* __restrict__ hist8, u64* __restrict__ flags, u64* __restrict__ flag2,
    u64* __restrict__ grpf) {
  __shared__ u32 wmn[4], wmx[4];
  int t = threadIdx.x;
  int i = blockIdx.x * 256 + t;
  // zero the 4 MB sliced histogram (2 x uint4 per thread, coalesced)
  uint4 z = make_uint4(0u, 0u, 0u, 0u);
  ((uint4*)hist8)[i] = z;
  ((uint4*)hist8)[i + N_ITEMS] = z;
  if (i < MBLK) flags[(size_t)i * FPAD] = 0ull;
  if (i < MBLK) flag2[(size_t)i * FPAD] = 0ull;
  if (i < 8) grpf[(size_t)i * FPAD] = 0ull;
  float xv = x[i];
  float s = b2[0];
#pragma unroll
  for (int j = 0; j < 32; ++j) {
    float h = fmaf(xv, w1[j], b1[j]);
    h = fmaxf(h, 0.0f);
    s = fmaf(h, w2[j], s);
  }
  u32 u = __float_as_uint(s);
  u32 m = u ^ ((u & 0x80000000u) ? 0xFFFFFFFFu : 0x80000000u); // ascending map
  u32 key = ~m;
  keyRaw[i] = key;
  u32 mn = key, mx = key;
#pragma unroll
  for (int off = 32; off > 0; off >>= 1) {
    mn = min(mn, (u32)__shfl_xor((int)mn, off));
    mx = max(mx, (u32)__shfl_xor((int)mx, off));
  }
  if ((t & 63) == 0) { wmn[t >> 6] = mn; wmx[t >> 6] = mx; }
  __syncthreads();
  if (t == 0) {
    mn = min(min(wmn[0], wmn[1]), min(wmn[2], wmn[3]));
    mx = max(max(wmx[0], wmx[1]), max(wmx[2], wmx[3]));
    pmin[blockIdx.x] = mn;
    pmax[blockIdx.x] = mx;
  }
}

// ---------- 2) bucket aggregates: ONE packed u64 atomic per item, XCD-sliced ----------
// bits [46:63] = count, bits [0:45] = fixed-point (2^28) sum of exp(s - smax)

__global__ __launch_bounds__(256) void hist_kernel(
    const u32* __restrict__ keyRaw,
    const u32* __restrict__ pmin, const u32* __restrict__ pmax,
    u64* __restrict__ hist8, u32* __restrict__ mm) {
  __shared__ u32 s0[256], s1[256];
  int t = threadIdx.x;
  s0[t] = min(pmin[t], pmin[t + 256]);
  s1[t] = max(pmax[t], pmax[t + 256]);
  __syncthreads();
  for (int off = 128; off > 0; off >>= 1) {
    if (t < off) { s0[t] = min(s0[t], s0[t + off]); s1[t] = max(s1[t], s1[t + off]); }
    __syncthreads();
  }
  u32 kmin = s0[0], kmax = s1[0];
  if (blockIdx.x == 0 && t == 0) { mm[0] = kmin; mm[1] = kmax; }
  int i = blockIdx.x * 256 + t;
  u32 key = keyRaw[i];
  u32 g = bucket_of(key, kmin, kmax);
  float smax = key_to_score(kmin);
  float v = fexp(key_to_score(key) - smax);            // in (0, 1]
  u64 fix = (u64)fmaxf(1.0f, fmaf(v, FIXSCALE, 0.5f)); // clamp: SY can never be 0
  size_t slice = (size_t)(blockIdx.x & (NSLICE - 1)) * NB;
  atomicAdd(&hist8[slice + g], (1ull << 46) | fix);
}

// ---------- 3) scan + PAV + in-LDS merges + leader region merges (fused) ----------
// 64 blocks. After publishing region stacks, non-leaders exit; leaders (b%8==0)
// poll 7 member lines (1 poller/line), merge via proven global merge_step;
// block 0 polls 7 group lines and finishes. No idle pollers, no extra dispatch.

__global__ __launch_bounds__(256) void scan_pav_merge_kernel(
    const u64* __restrict__ hist8, u64* __restrict__ flags, u64* __restrict__ flag2,
    u64* __restrict__ grpf, u32* __restrict__ cdf, int2* __restrict__ REC,
    int* __restrict__ cnt2) {
  __shared__ u32 vals[BUCK_PER_BLK + 1];   // counts -> global-exclusive cdf
  __shared__ float seL[BUCK_PER_BLK];
  __shared__ int   rST[CH_PER_BLK * PAD];
  __shared__ float rSY[CH_PER_BLK * PAD];
  __shared__ u32 wsum[4];
  __shared__ u32 regS[65];
  __shared__ int lcnt[CH_PER_BLK];
  __shared__ int ca[16], cb[16], cM[16];
  __shared__ int shInt[4];
  __shared__ int pm[8];
  int t = threadIdx.x, b = blockIdx.x;
  int B0 = b * BUCK_PER_BLK;
  // coalesced load + slice reduce
  for (int q = 0; q < 8; ++q) {
    int ii = q * 256 + t;
    u64 acc = 0;
#pragma unroll
    for (int c = 0; c < NSLICE; ++c) acc += hist8[(size_t)c * NB + B0 + ii];
    vals[ii] = (u32)(acc >> 46);
    seL[ii] = (float)(acc & FIXMASK) * (1.0f / FIXSCALE);
  }
  __syncthreads();
  // per-thread local prefix over contiguous 8, then wave shfl scan + 4-wave combine
  u32 loc[8]; u32 s = 0;
  for (int q = 0; q < 8; ++q) { loc[q] = s; s += vals[t * 8 + q]; }
  u32 inc = s;
#pragma unroll
  for (int off = 1; off < 64; off <<= 1) {
    u32 o2 = (u32)__shfl_up((int)inc, off);
    if ((t & 63) >= off) inc += o2;
  }
  if ((t & 63) == 63) wsum[t >> 6] = inc;
  __syncthreads();
  u32 w = (u32)(t >> 6);
  u32 woff = 0;
  if (w > 0) woff += wsum[0];
  if (w > 1) woff += wsum[1];
  if (w > 2) woff += wsum[2];
  u32 total = wsum[0] + wsum[1] + wsum[2] + wsum[3];
  u32 texcl = woff + inc - s;
  // publish aggregate; wait-all over 64 blocks (64 distinct lines, 64 pollers: safe)
  if (t == 0) atomicExch(&flags[(size_t)b * FPAD], (1ull << 32) | (u64)total);
  if (t < 64) {
    u64 f;
    do { f = agent_ld(&flags[(size_t)t * FPAD]); } while ((u32)(f >> 32) == 0u);
    u32 v = (u32)f, inc2 = v;
#pragma unroll
    for (int off = 1; off < 64; off <<= 1) {
      u32 o2 = (u32)__shfl_up((int)inc2, off);
      if (t >= off) inc2 += o2;
    }
    regS[t] = inc2 - v;
    if (t == 63) regS[64] = inc2;          // == N_ITEMS
  }
  __syncthreads();
  u32 exclu = regS[b];
  u32 tbase = texcl + exclu;
  // overwrite vals with GLOBAL exclusive cdf; mirror to global (vectorized)
  u32 eb8[8];
  for (int q = 0; q < 8; ++q) { eb8[q] = tbase + loc[q]; vals[t * 8 + q] = eb8[q]; }
  {
    uint4* c4 = (uint4*)(cdf + B0 + t * 8);
    c4[0] = make_uint4(eb8[0], eb8[1], eb8[2], eb8[3]);
    c4[1] = make_uint4(eb8[4], eb8[5], eb8[6], eb8[7]);
  }
  if (t == 255) vals[BUCK_PER_BLK] = exclu + total;
  __syncthreads();
  // per-chunk PAV (32 threads), stack stored in place at padded stride
  if (t < CH_PER_BLK) {
    int base = t * PAD;
    int ptr = 0; bool have = false;
    float syT = 0.0f; int stT = 0;
    for (int k = 0; k < 64; ++k) {
      u32 cs = vals[t * 64 + k], ce = vals[t * 64 + k + 1];
      if (ce == cs) continue;                 // empty bucket
      float syC = seL[t * 64 + k];
      int stC = (int)cs, eC = (int)ce - 1;
      while (have) {
        float SWc = wsumf(stC, eC);
        float SWt = wsumf(stT, stC - 1);
        if (!(syT * SWc <= syC * SWt)) break; // merge while val_top <= val_cur
        syC += syT; stC = stT;
        if (ptr == 0) { have = false; break; }
        --ptr;
        stT = rST[base + ptr]; syT = rSY[base + ptr];
      }
      if (have) { rST[base + ptr] = stT; rSY[base + ptr] = syT; ++ptr; }
      stT = stC; syT = syC; have = true;
    }
    if (have) { rST[base + ptr] = stT; rSY[base + ptr] = syT; ++ptr; }
    lcnt[t] = ptr;
  }
  __syncthreads();
  // merge levels 0..4 entirely in LDS; copies wave-parallel across disjoint pairs
  for (int j = 0; j < 5; ++j) {
    int P = CH_PER_BLK >> (j + 1);
    if (t < P) {
      int p = t;
      int kL = p << (j + 1), kR = kL + (1 << j);
      int slotL = kL * PAD, slotR = kR * PAD;
      int nL = lcnt[kL], nR = lcnt[kR];
      int a = 0, bb = 0, hasM = 0;
      if (nL > 0 && nR > 0) {
        int gstartR = (int)vals[kR * 64];
        int gendR   = (int)vals[(kR + (1 << j)) * 64];
        float SYL = rSY[slotL + nL - 1]; int stL = rST[slotL + nL - 1];
        float SYR = rSY[slotR];
        int eR = (nR > 1) ? (rST[slotR + 1] - 1) : (gendR - 1);
        float SWL = wsumf(stL, gstartR - 1);
        float SWR = wsumf(gstartR, eR);
        if (SYL * SWR <= SYR * SWL) {
          hasM = 1;
          float SYM = SYL + SYR; int Ms = stL, Me = eR;
          a = 1; bb = 1;
          for (;;) {
            float SWM = wsumf(Ms, Me);
            if (a < nL) {
              float SYe = rSY[slotL + nL - 1 - a]; int ste = rST[slotL + nL - 1 - a];
              float SWe = wsumf(ste, Ms - 1);
              if (SYe * SWM <= SYM * SWe) { SYM += SYe; Ms = ste; ++a; continue; }
            }
            if (bb < nR) {
              float SYb = rSY[slotR + bb]; int sb = rST[slotR + bb];
              int eb = (bb + 1 < nR) ? (rST[slotR + bb + 1] - 1) : (gendR - 1);
              float SWb = wsumf(sb, eb);
              if (SYM * SWb <= SYb * SWM) { SYM += SYb; Me = eb; ++bb; continue; }
            }
            break;
          }
          rST[slotL + nL - a] = Ms; rSY[slotL + nL - a] = SYM;
        }
      }
      ca[p] = a; cb[p] = bb; cM[p] = hasM;
    }
    __syncthreads();
    {
      int wv = t >> 6, lane = t & 63;
      for (int p = wv; p < P; p += 4) {      // pairs disjoint -> waves in parallel
        int kL = p << (j + 1), kR = kL + (1 << j);
        int nL = lcnt[kL], nR = lcnt[kR];
        int a = ca[p], bb = cb[p], hasM = cM[p];
        int destBase = kL * PAD + nL - a + hasM;
        int srcBase = kR * PAD + bb;
        int ncopy = nR - bb;
        for (int off = 0; off < ncopy; off += 64) {  // wave-staged, dest<=src, in order
          int k2 = off + lane; bool act = k2 < ncopy;
          int vt = 0; float vs = 0.f;
          if (act) { vt = rST[srcBase + k2]; vs = rSY[srcBase + k2]; }
          if (act) { rST[destBase + k2] = vt; rSY[destBase + k2] = vs; }
        }
      }
    }
    __syncthreads();
    if (t < P) {
      int p = t; int kL = p << (j + 1), kR = kL + (1 << j);
      lcnt[kL] = lcnt[kL] - ca[p] + cM[p] + (lcnt[kR] - cb[p]);
    }
    __syncthreads();
  }
  // write region records (coalesced)
  int n = lcnt[0];
  for (int k = t; k < n; k += 256)
    REC[(size_t)b * REGSLOT + k] = make_int2(rST[k], __float_as_int(rSY[k]));
  __syncthreads();
  // ---- publish region stack + count; non-leaders exit ----
  if (t == 0) { __threadfence(); atomicExch(&flag2[(size_t)b * FPAD], (1ull << 32) | (u64)(u32)n); }
  if ((b & 7) != 0) return;
  // ---- group merge (leaders): 7 member lines, 1 poller each ----
  if (t < 7) {
    u64 f;
    do { f = agent_ld(&flag2[(size_t)(b + 1 + t) * FPAD]); } while ((u32)(f >> 32) == 0u);
    pm[1 + t] = (int)(u32)f;
  }
  __syncthreads();
  __threadfence();                       // acquire member stacks
  int nL = n;
  for (int k = 1; k < 8; ++k)
    nL = merge_step(REC, b * REGSLOT, nL, (b + k) * REGSLOT, pm[k],
                    (int)regS[b + k], (int)regS[b + k + 1], t, shInt);
  if (t == 0) { __threadfence(); atomicExch(&grpf[(size_t)(b >> 3) * FPAD], (1ull << 32) | (u64)(u32)nL); }
  if (b != 0) return;
  // ---- final merge (block 0): 7 group lines, 1 poller each ----
  if (t < 7) {
    u64 f;
    do { f = agent_ld(&grpf[(size_t)(1 + t) * FPAD]); } while ((u32)(f >> 32) == 0u);
    pm[1 + t] = (int)(u32)f;
  }
  __syncthreads();
  __threadfence();                       // acquire the 7 group stacks
  for (int k = 1; k < 8; ++k)
    nL = merge_step(REC, 0, nL, (k * 8) * REGSLOT, pm[k],
                    (int)regS[k * 8], (int)regS[k * 8 + 8], t, shInt);
  if (t == 0) cnt2[0] = nL;              // kernel boundary publishes to out_kernel
}

// ---------- 4) ranks + transform; LDS-staged search table; coalesced output ----------

__global__ __launch_bounds__(256) void out_kernel(
    const u32* __restrict__ keyRaw, const u32* __restrict__ mm,
    const u32* __restrict__ cdf, const int2* __restrict__ REC,
    const int* __restrict__ cnt2, float* __restrict__ out) {
  __shared__ int   rST[CAPO];
  __shared__ float rSY[CAPO];
  int t = threadIdx.x;
  int i = blockIdx.x * 256 + t;
  int m = cnt2[0];
  u32 kmin = mm[0], kmax = mm[1];
  u32 key = keyRaw[i];
  float smax = key_to_score(kmin);
  u32 g = bucket_of(key, kmin, kmax);
  int p = (int)cdf[g];               // bucket-aligned: position of bucket start
  bool useL = (m <= CAPO);
  if (useL) {
    for (int k = t; k < m; k += 256) {
      int2 r = REC[k];
      rST[k] = r.x; rSY[k] = __int_as_float(r.y);
    }
  }
  __syncthreads();
  int lo = 0, hi = m - 1;
  if (useL) {
    while (lo < hi) {
      int mid = (lo + hi + 1) >> 1;
      if (rST[mid] <= p) lo = mid; else hi = mid - 1;
    }
    int s0 = rST[lo];
    int e0 = (lo + 1 < m) ? (rST[lo + 1] - 1) : (N_ITEMS - 1);
    float SW = wsumf(s0, e0);
    float rank = fexp(key_to_score(key) - smax) * SW / rSY[lo];
    out[i] = floorf(rank * (1.0f / 3.0f)) + 1.0f;
  } else {
    while (lo < hi) {
      int mid = (lo + hi + 1) >> 1;
      if (REC[mid].x <= p) lo = mid; else hi = mid - 1;
    }
    int2 r = REC[lo];
    int s0 = r.x;
    int e0 = (lo + 1 < m) ? (REC[lo + 1].x - 1) : (N_ITEMS - 1);
    float SW = wsumf(s0, e0);
    float rank = fexp(key_to_score(key) - smax) * SW / recSY(r);
    out[i] = floorf(rank * (1.0f / 3.0f)) + 1.0f;
  }
}

// ---------- launch ----------

extern "C" void kernel_launch(void* const* d_in, const int* in_sizes, int n_in,
                              void* d_out, int out_size, void* d_ws, size_t ws_size,
                              hipStream_t stream) {
  const float* x  = (const float*)d_in[0];
  const float* w1 = (const float*)d_in[1];
  const float* b1 = (const float*)d_in[2];
  const float* w2 = (const float*)d_in[3];
  const float* b2 = (const float*)d_in[4];
  float* out = (float*)d_out;

  char* ws = (char*)d_ws;
  size_t o = 0;
  u32* mm     = (u32*)(ws + o); o += 64;
  u32* pmin   = (u32*)(ws + o); o += (size_t)512 * 4;
  u32* pmax   = (u32*)(ws + o); o += (size_t)512 * 4;
  u32* cdf    = (u32*)(ws + o); o += (size_t)(NB + 4) * 4;
  u32* keyRaw = (u32*)(ws + o); o += (size_t)N_ITEMS * 4;
  int2* REC   = (int2*)(ws + o); o += (size_t)N_ITEMS * 8;
  int* cnt2   = (int*)(ws + o);  o += (size_t)MBLK * 4;
  u64* hist8  = (u64*)(ws + o); o += (size_t)NSLICE * NB * 8;    // 4 MB, zeroed in k1
  u64* flags  = (u64*)(ws + o); o += (size_t)MBLK * FPAD * 8;    // zeroed in k1
  u64* flag2  = (u64*)(ws + o); o += (size_t)MBLK * FPAD * 8;    // zeroed in k1
  u64* grpf   = (u64*)(ws + o); o += (size_t)8 * FPAD * 8;       // zeroed in k1

  score_key_kernel<<<512, 256, 0, stream>>>(x, w1, b1, w2, b2, keyRaw,
                                            pmin, pmax, hist8, flags, flag2, grpf);
  hist_kernel<<<512, 256, 0, stream>>>(keyRaw, pmin, pmax, hist8, mm);
  scan_pav_merge_kernel<<<MBLK, 256, 0, stream>>>(hist8, flags, flag2, grpf,
                                                  cdf, REC, cnt2);
  out_kernel<<<512, 256, 0, stream>>>(keyRaw, mm, cdf, REC, cnt2, out);
}